// Round 1
// baseline (661.888 us; speedup 1.0000x reference)
//
#include <hip/hip_runtime.h>
#include <stdint.h>

#define N_NODES 20000
#define K_NB 32
#define D_DIM 128

typedef short bf16x8 __attribute__((ext_vector_type(8)));
typedef float f32x4 __attribute__((ext_vector_type(4)));

// fp32 -> bf16 round-to-nearest-even
__device__ __forceinline__ unsigned short f2bf(float f) {
    union { float f; unsigned u; } v; v.f = f;
    unsigned r = v.u + 0x7FFFu + ((v.u >> 16) & 1u);
    return (unsigned short)(r >> 16);
}

__device__ __forceinline__ bf16x8 pack8(float4 a, float4 b) {
    bf16x8 r;
    r[0] = (short)f2bf(a.x); r[1] = (short)f2bf(a.y);
    r[2] = (short)f2bf(a.z); r[3] = (short)f2bf(a.w);
    r[4] = (short)f2bf(b.x); r[5] = (short)f2bf(b.y);
    r[6] = (short)f2bf(b.z); r[7] = (short)f2bf(b.w);
    return r;
}

__device__ __forceinline__ float dot16(float4 a0, float4 a1, float4 a2, float4 a3,
                                       float4 b0, float4 b1, float4 b2, float4 b3) {
    return a0.x*b0.x + a0.y*b0.y + a0.z*b0.z + a0.w*b0.w
         + a1.x*b1.x + a1.y*b1.y + a1.z*b1.z + a1.w*b1.w
         + a2.x*b2.x + a2.y*b2.y + a2.z*b2.z + a2.w*b2.w
         + a3.x*b3.x + a3.y*b3.y + a3.z*b3.z + a3.w*b3.w;
}

__device__ __forceinline__ float sigm(float x) {
    return __builtin_amdgcn_rcpf(1.0f + __expf(-x));
}

#define A_STRIDE 136
#define NG_STRIDE 132

// ---------------------------------------------------------------------------
// Kernel 1: tsf[n,e] = self_feats @ self_weights ; ts[n] = self_vecs . gate_self_w
// ---------------------------------------------------------------------------
__global__ __launch_bounds__(256) void precompute_kernel(
    const float* __restrict__ self_feats,
    const float* __restrict__ self_vecs,
    const float* __restrict__ gate_self_w,
    const float* __restrict__ self_weights,
    float* __restrict__ tsf,
    float* __restrict__ ts)
{
    __shared__ __align__(16) unsigned short A[32 * A_STRIDE];

    const int tid  = threadIdx.x;
    const int lane = tid & 63;
    const int w    = tid >> 6;
    const int q    = lane >> 4;
    const int el   = lane & 15;
    const int row  = tid >> 3;
    const int seg  = tid & 7;
    const int node0 = blockIdx.x * 32;

    bf16x8 wf[2][4];
#pragma unroll
    for (int nt = 0; nt < 2; ++nt) {
        int e = 32 * w + 16 * nt + el;
#pragma unroll
        for (int s = 0; s < 4; ++s) {
#pragma unroll
            for (int j = 0; j < 8; ++j) {
                int d = 32 * s + 8 * q + j;
                wf[nt][s][j] = (short)f2bf(self_weights[d * 128 + e]);
            }
        }
    }

    const float4* gs = (const float4*)(gate_self_w + seg * 16);
    float4 g0 = gs[0], g1 = gs[1], g2 = gs[2], g3 = gs[3];

    {
        const float4* sfr = (const float4*)(self_feats + (size_t)(node0 + row) * 128 + seg * 16);
        float4 v0 = sfr[0], v1 = sfr[1], v2 = sfr[2], v3 = sfr[3];
        const float4* svr = (const float4*)(self_vecs + (size_t)(node0 + row) * 128 + seg * 16);
        float4 u0 = svr[0], u1 = svr[1], u2 = svr[2], u3 = svr[3];

        float part = dot16(u0, u1, u2, u3, g0, g1, g2, g3);
        part += __shfl_xor(part, 1);
        part += __shfl_xor(part, 2);
        part += __shfl_xor(part, 4);
        if (seg == 0) ts[node0 + row] = part;

        *(bf16x8*)&A[row * A_STRIDE + seg * 16]     = pack8(v0, v1);
        *(bf16x8*)&A[row * A_STRIDE + seg * 16 + 8] = pack8(v2, v3);
    }
    __syncthreads();

    f32x4 acc[2][2] = {};
#pragma unroll
    for (int s = 0; s < 4; ++s) {
        bf16x8 a0 = *(const bf16x8*)&A[(el)      * A_STRIDE + 32 * s + 8 * q];
        bf16x8 a1 = *(const bf16x8*)&A[(16 + el) * A_STRIDE + 32 * s + 8 * q];
        acc[0][0] = __builtin_amdgcn_mfma_f32_16x16x32_bf16(a0, wf[0][s], acc[0][0], 0, 0, 0);
        acc[0][1] = __builtin_amdgcn_mfma_f32_16x16x32_bf16(a0, wf[1][s], acc[0][1], 0, 0, 0);
        acc[1][0] = __builtin_amdgcn_mfma_f32_16x16x32_bf16(a1, wf[0][s], acc[1][0], 0, 0, 0);
        acc[1][1] = __builtin_amdgcn_mfma_f32_16x16x32_bf16(a1, wf[1][s], acc[1][1], 0, 0, 0);
    }

#pragma unroll
    for (int mt = 0; mt < 2; ++mt)
#pragma unroll
        for (int nt = 0; nt < 2; ++nt)
#pragma unroll
            for (int r = 0; r < 4; ++r) {
                int m = 16 * mt + 4 * q + r;
                tsf[(size_t)(node0 + m) * 128 + 32 * w + 16 * nt + el] = acc[mt][nt][r];
            }
}

// ---------------------------------------------------------------------------
// Kernel 2: fused aggregation, software-pipelined node loop.
// 2 barriers/node; next node's 32KB global load is in flight during
// MFMA+epilogue of the current node.
// __launch_bounds__(256,3): cap VGPR <=170 so 3 waves/SIMD are resident
// (live-reg accounting: was ~180 -> 2 waves/SIMD, latency exposed).
// ---------------------------------------------------------------------------
__global__ __launch_bounds__(256, 3) void aggregate_kernel(
    const float* __restrict__ neigh_vecs,
    const float* __restrict__ link_vecs,
    const float* __restrict__ select_probs,
    const float* __restrict__ gate_neigh_w,
    const float* __restrict__ gate_link_w,
    const float* __restrict__ link_weights,
    const float* __restrict__ tsf,
    const float* __restrict__ ts,
    float* __restrict__ out)
{
    __shared__ __align__(16) unsigned short A[32 * A_STRIDE];
    __shared__ __align__(16) float NG[32 * NG_STRIDE];
    __shared__ float t_s[32];    // trans_neigh + trans_link per neighbor
    __shared__ float sp_s[32];   // 1 / (32 * select_prob)

    const int tid  = threadIdx.x;
    const int lane = tid & 63;
    const int w    = tid >> 6;
    const int q    = lane >> 4;
    const int el   = lane & 15;
    const int row  = tid >> 3;
    const int seg  = tid & 7;

    // link_weights B-fragments: registers for the whole block
    bf16x8 wf[2][4];
#pragma unroll
    for (int nt = 0; nt < 2; ++nt) {
        int e = 32 * w + 16 * nt + el;
#pragma unroll
        for (int s = 0; s < 4; ++s) {
#pragma unroll
            for (int j = 0; j < 8; ++j) {
                int d = 32 * s + 8 * q + j;
                wf[nt][s][j] = (short)f2bf(link_weights[d * 128 + e]);
            }
        }
    }

    const float4* glp = (const float4*)(gate_link_w + seg * 16);
    float4 gl0 = glp[0], gl1 = glp[1], gl2 = glp[2], gl3 = glp[3];
    const float4* gnp = (const float4*)(gate_neigh_w + seg * 16);
    float4 gn0 = gnp[0], gn1 = gnp[1], gn2 = gnp[2], gn3 = gnp[3];

    const int stride = gridDim.x;

    // ---- prologue prefetch: node n0 ----
    float4 v0, v1, v2, v3, u0, u1, u2, u3;
    float sp_r = 1.0f, ts_r = 0.0f, tsf_r0 = 0.0f, tsf_r1 = 0.0f;
    {
        int n = blockIdx.x;
        const float4* lr = (const float4*)(link_vecs + ((size_t)n * 32 + row) * 128 + seg * 16);
        v0 = lr[0]; v1 = lr[1]; v2 = lr[2]; v3 = lr[3];
        const float4* nr = (const float4*)(neigh_vecs + ((size_t)n * 32 + row) * 128 + seg * 16);
        u0 = nr[0]; u1 = nr[1]; u2 = nr[2]; u3 = nr[3];
        if (tid < 32) sp_r = select_probs[(size_t)n * 32 + tid];
        ts_r   = ts[n];
        tsf_r0 = tsf[(size_t)n * 128 + 32 * w + el];
        tsf_r1 = tsf[(size_t)n * 128 + 32 * w + 16 + el];
    }

    for (int n = blockIdx.x; n < N_NODES; n += stride) {
        // ---- phase W: stage prefetched regs into LDS + gate dots ----
        float tl = dot16(v0, v1, v2, v3, gl0, gl1, gl2, gl3);
        tl += __shfl_xor(tl, 1);
        tl += __shfl_xor(tl, 2);
        tl += __shfl_xor(tl, 4);
        float tn = dot16(u0, u1, u2, u3, gn0, gn1, gn2, gn3);
        tn += __shfl_xor(tn, 1);
        tn += __shfl_xor(tn, 2);
        tn += __shfl_xor(tn, 4);
        if (seg == 0) t_s[row] = tl + tn;
        if (tid < 32) sp_s[tid] = __builtin_amdgcn_rcpf(32.0f * sp_r);

        *(bf16x8*)&A[row * A_STRIDE + seg * 16]     = pack8(v0, v1);
        *(bf16x8*)&A[row * A_STRIDE + seg * 16 + 8] = pack8(v2, v3);
        float4* ngp = (float4*)&NG[row * NG_STRIDE + seg * 16];
        ngp[0] = u0; ngp[1] = u1; ngp[2] = u2; ngp[3] = u3;

        // keep this node's scalars before the prefetch overwrites the regs
        float ts_cur = ts_r, tc0 = tsf_r0, tc1 = tsf_r1;

        __syncthreads();

        // ---- issue next node's global loads (in flight during compute) ----
        {
            int np = n + stride;
            np = (np < N_NODES) ? np : n;
            const float4* lr = (const float4*)(link_vecs + ((size_t)np * 32 + row) * 128 + seg * 16);
            v0 = lr[0]; v1 = lr[1]; v2 = lr[2]; v3 = lr[3];
            const float4* nr = (const float4*)(neigh_vecs + ((size_t)np * 32 + row) * 128 + seg * 16);
            u0 = nr[0]; u1 = nr[1]; u2 = nr[2]; u3 = nr[3];
            if (tid < 32) sp_r = select_probs[(size_t)np * 32 + tid];
            ts_r   = ts[np];
            tsf_r0 = tsf[(size_t)np * 128 + 32 * w + el];
            tsf_r1 = tsf[(size_t)np * 128 + 32 * w + 16 + el];
        }

        // ---- MFMA: C[m][e] = link_row_m . W[:,e] ----
        // af fragments loaded per-K-subtile to cut peak VGPR liveness
        // (was: all 8 up-front = +24 live regs -> occupancy cliff)
        f32x4 acc[2][2] = {};
#pragma unroll
        for (int s = 0; s < 4; ++s) {
            bf16x8 a0 = *(const bf16x8*)&A[(el)      * A_STRIDE + 32 * s + 8 * q];
            bf16x8 a1 = *(const bf16x8*)&A[(16 + el) * A_STRIDE + 32 * s + 8 * q];
            acc[0][0] = __builtin_amdgcn_mfma_f32_16x16x32_bf16(a0, wf[0][s], acc[0][0], 0, 0, 0);
            acc[0][1] = __builtin_amdgcn_mfma_f32_16x16x32_bf16(a0, wf[1][s], acc[0][1], 0, 0, 0);
            acc[1][0] = __builtin_amdgcn_mfma_f32_16x16x32_bf16(a1, wf[0][s], acc[1][0], 0, 0, 0);
            acc[1][1] = __builtin_amdgcn_mfma_f32_16x16x32_bf16(a1, wf[1][s], acc[1][1], 0, 0, 0);
        }

        // ---- per-lane gate weights: g[m] = sigmoid(ts + t[m]) / (32 p[m]) ----
        float g[2][4];
#pragma unroll
        for (int mt = 0; mt < 2; ++mt)
#pragma unroll
            for (int r = 0; r < 4; ++r) {
                int m = 16 * mt + 4 * q + r;
                g[mt][r] = sigm(ts_cur + t_s[m]) * sp_s[m];
            }

        // ---- epilogue: sigmoid(C) * neigh * g, reduce over 32 rows ----
#pragma unroll
        for (int nt = 0; nt < 2; ++nt) {
            int c0 = 32 * w + 16 * nt;
            float s = 0.0f;
#pragma unroll
            for (int mt = 0; mt < 2; ++mt)
#pragma unroll
                for (int r = 0; r < 4; ++r) {
                    int m = 16 * mt + 4 * q + r;
                    float t = sigm(acc[mt][nt][r]);
                    s += t * NG[m * NG_STRIDE + c0 + el] * g[mt][r];
                }
            s += __shfl_xor(s, 16);
            s += __shfl_xor(s, 32);
            if (q == 0) {
                float tc = nt == 0 ? tc0 : tc1;
                float o = tc * s;
                out[(size_t)n * 128 + c0 + el] = o > 0.0f ? o : 0.0f;
            }
        }

        __syncthreads();  // guard LDS against next iteration's phase W
    }
}

extern "C" void kernel_launch(void* const* d_in, const int* in_sizes, int n_in,
                              void* d_out, int out_size, void* d_ws, size_t ws_size,
                              hipStream_t stream) {
    const float* self_feats   = (const float*)d_in[0];
    const float* self_vecs    = (const float*)d_in[1];
    const float* neigh_vecs   = (const float*)d_in[2];
    const float* link_vecs    = (const float*)d_in[3];
    const float* select_probs = (const float*)d_in[4];
    const float* gate_self_w  = (const float*)d_in[5];
    const float* gate_neigh_w = (const float*)d_in[6];
    const float* gate_link_w  = (const float*)d_in[7];
    const float* self_weights = (const float*)d_in[8];
    const float* link_weights = (const float*)d_in[9];
    float* out = (float*)d_out;

    float* tsf = (float*)d_ws;                       // [N,128] fp32
    float* ts  = tsf + (size_t)N_NODES * D_DIM;      // [N] fp32

    precompute_kernel<<<N_NODES / 32, 256, 0, stream>>>(
        self_feats, self_vecs, gate_self_w, self_weights, tsf, ts);
    // grid 2048: finer block granularity (~10 nodes/block) so the tail
    // rebalances at whatever residency the VGPR count allows.
    aggregate_kernel<<<2048, 256, 0, stream>>>(
        neigh_vecs, link_vecs, select_probs, gate_neigh_w, gate_link_w,
        link_weights, tsf, ts, out);
}

// Round 2
// 660.953 us; speedup vs baseline: 1.0014x; 1.0014x over previous
//
#include <hip/hip_runtime.h>
#include <stdint.h>

#define N_NODES 20000
#define K_NB 32
#define D_DIM 128

typedef short bf16x8 __attribute__((ext_vector_type(8)));
typedef float f32x4 __attribute__((ext_vector_type(4)));

// fp32 -> bf16 round-to-nearest-even
__device__ __forceinline__ unsigned short f2bf(float f) {
    union { float f; unsigned u; } v; v.f = f;
    unsigned r = v.u + 0x7FFFu + ((v.u >> 16) & 1u);
    return (unsigned short)(r >> 16);
}

__device__ __forceinline__ bf16x8 pack8(float4 a, float4 b) {
    bf16x8 r;
    r[0] = (short)f2bf(a.x); r[1] = (short)f2bf(a.y);
    r[2] = (short)f2bf(a.z); r[3] = (short)f2bf(a.w);
    r[4] = (short)f2bf(b.x); r[5] = (short)f2bf(b.y);
    r[6] = (short)f2bf(b.z); r[7] = (short)f2bf(b.w);
    return r;
}

__device__ __forceinline__ float dot16(float4 a0, float4 a1, float4 a2, float4 a3,
                                       float4 b0, float4 b1, float4 b2, float4 b3) {
    return a0.x*b0.x + a0.y*b0.y + a0.z*b0.z + a0.w*b0.w
         + a1.x*b1.x + a1.y*b1.y + a1.z*b1.z + a1.w*b1.w
         + a2.x*b2.x + a2.y*b2.y + a2.z*b2.z + a2.w*b2.w
         + a3.x*b3.x + a3.y*b3.y + a3.z*b3.z + a3.w*b3.w;
}

__device__ __forceinline__ float sigm(float x) {
    return __builtin_amdgcn_rcpf(1.0f + __expf(-x));
}

__device__ __forceinline__ float4 scale4(float4 a, float s) {
    float4 r; r.x = a.x*s; r.y = a.y*s; r.z = a.z*s; r.w = a.w*s; return r;
}

#define A_STRIDE 136
#define NG_STRIDE 132

// ---------------------------------------------------------------------------
// Kernel 1: tsf[n,e] = self_feats @ self_weights ; ts[n] = self_vecs . gate_self_w
// ---------------------------------------------------------------------------
__global__ __launch_bounds__(256) void precompute_kernel(
    const float* __restrict__ self_feats,
    const float* __restrict__ self_vecs,
    const float* __restrict__ gate_self_w,
    const float* __restrict__ self_weights,
    float* __restrict__ tsf,
    float* __restrict__ ts)
{
    __shared__ __align__(16) unsigned short A[32 * A_STRIDE];

    const int tid  = threadIdx.x;
    const int lane = tid & 63;
    const int w    = tid >> 6;
    const int q    = lane >> 4;
    const int el   = lane & 15;
    const int row  = tid >> 3;
    const int seg  = tid & 7;
    const int node0 = blockIdx.x * 32;

    bf16x8 wf[2][4];
#pragma unroll
    for (int nt = 0; nt < 2; ++nt) {
        int e = 32 * w + 16 * nt + el;
#pragma unroll
        for (int s = 0; s < 4; ++s) {
#pragma unroll
            for (int j = 0; j < 8; ++j) {
                int d = 32 * s + 8 * q + j;
                wf[nt][s][j] = (short)f2bf(self_weights[d * 128 + e]);
            }
        }
    }

    const float4* gs = (const float4*)(gate_self_w + seg * 16);
    float4 g0 = gs[0], g1 = gs[1], g2 = gs[2], g3 = gs[3];

    {
        const float4* sfr = (const float4*)(self_feats + (size_t)(node0 + row) * 128 + seg * 16);
        float4 v0 = sfr[0], v1 = sfr[1], v2 = sfr[2], v3 = sfr[3];
        const float4* svr = (const float4*)(self_vecs + (size_t)(node0 + row) * 128 + seg * 16);
        float4 u0 = svr[0], u1 = svr[1], u2 = svr[2], u3 = svr[3];

        float part = dot16(u0, u1, u2, u3, g0, g1, g2, g3);
        part += __shfl_xor(part, 1);
        part += __shfl_xor(part, 2);
        part += __shfl_xor(part, 4);
        if (seg == 0) ts[node0 + row] = part;

        *(bf16x8*)&A[row * A_STRIDE + seg * 16]     = pack8(v0, v1);
        *(bf16x8*)&A[row * A_STRIDE + seg * 16 + 8] = pack8(v2, v3);
    }
    __syncthreads();

    f32x4 acc[2][2] = {};
#pragma unroll
    for (int s = 0; s < 4; ++s) {
        bf16x8 a0 = *(const bf16x8*)&A[(el)      * A_STRIDE + 32 * s + 8 * q];
        bf16x8 a1 = *(const bf16x8*)&A[(16 + el) * A_STRIDE + 32 * s + 8 * q];
        acc[0][0] = __builtin_amdgcn_mfma_f32_16x16x32_bf16(a0, wf[0][s], acc[0][0], 0, 0, 0);
        acc[0][1] = __builtin_amdgcn_mfma_f32_16x16x32_bf16(a0, wf[1][s], acc[0][1], 0, 0, 0);
        acc[1][0] = __builtin_amdgcn_mfma_f32_16x16x32_bf16(a1, wf[0][s], acc[1][0], 0, 0, 0);
        acc[1][1] = __builtin_amdgcn_mfma_f32_16x16x32_bf16(a1, wf[1][s], acc[1][1], 0, 0, 0);
    }

#pragma unroll
    for (int mt = 0; mt < 2; ++mt)
#pragma unroll
        for (int nt = 0; nt < 2; ++nt)
#pragma unroll
            for (int r = 0; r < 4; ++r) {
                int m = 16 * mt + 4 * q + r;
                tsf[(size_t)(node0 + m) * 128 + 32 * w + 16 * nt + el] = acc[mt][nt][r];
            }
}

// ---------------------------------------------------------------------------
// Kernel 2: fused aggregation with 2-DEEP register prefetch.
// Two named prefetch sets (PA/PB), loop unrolled x2 (no runtime indexing ->
// no scratch). Every iteration issues a 32KB burst whose landing deadline is
// 2 iterations away, so the younger set stays in flight across the phase-W
// vmcnt wait -> memory queue never drains (was: 1-deep, ~45% duty cycle,
// 1.83 TB/s).
// g-premultiplication: gate weight per neighbor row computed ONCE in phase W
// (all 8 seg-threads own t after the shfl reduce) and folded into the LDS
// neigh tile -> epilogue sigmoid count 16->8 per thread, t_s/sp_s removed.
// ---------------------------------------------------------------------------
struct Pref {
    float4 v0, v1, v2, v3;   // link_vecs row slice
    float4 u0, u1, u2, u3;   // neigh_vecs row slice
    float sp, ts, t0, t1;
};

__device__ __forceinline__ void load_node(
    Pref& P, int n, int row, int seg, int w, int el,
    const float* __restrict__ link_vecs, const float* __restrict__ neigh_vecs,
    const float* __restrict__ select_probs, const float* __restrict__ ts,
    const float* __restrict__ tsf)
{
    const float4* lr = (const float4*)(link_vecs + ((size_t)n * 32 + row) * 128 + seg * 16);
    P.v0 = lr[0]; P.v1 = lr[1]; P.v2 = lr[2]; P.v3 = lr[3];
    const float4* nr = (const float4*)(neigh_vecs + ((size_t)n * 32 + row) * 128 + seg * 16);
    P.u0 = nr[0]; P.u1 = nr[1]; P.u2 = nr[2]; P.u3 = nr[3];
    P.sp = select_probs[(size_t)n * 32 + row];   // 8 threads/row broadcast-read
    P.ts = ts[n];
    P.t0 = tsf[(size_t)n * 128 + 32 * w + el];
    P.t1 = tsf[(size_t)n * 128 + 32 * w + 16 + el];
}

__device__ __forceinline__ void process_node(
    Pref& P, int n_cur, int n_next,
    int row, int seg, int w, int q, int el,
    unsigned short* A, float* NG,
    const bf16x8 (&wf)[2][4],
    float4 gl0, float4 gl1, float4 gl2, float4 gl3,
    float4 gn0, float4 gn1, float4 gn2, float4 gn3,
    const float* __restrict__ link_vecs, const float* __restrict__ neigh_vecs,
    const float* __restrict__ select_probs, const float* __restrict__ ts,
    const float* __restrict__ tsf, float* __restrict__ out)
{
    // ---- phase W: gate dots + stage prefetched regs into LDS ----
    float tl = dot16(P.v0, P.v1, P.v2, P.v3, gl0, gl1, gl2, gl3);
    tl += __shfl_xor(tl, 1);
    tl += __shfl_xor(tl, 2);
    tl += __shfl_xor(tl, 4);
    float tn = dot16(P.u0, P.u1, P.u2, P.u3, gn0, gn1, gn2, gn3);
    tn += __shfl_xor(tn, 1);
    tn += __shfl_xor(tn, 2);
    tn += __shfl_xor(tn, 4);
    // all 8 seg-threads of this row hold the full gate sum -> premultiply
    float g_row = sigm(P.ts + tl + tn) * __builtin_amdgcn_rcpf(32.0f * P.sp);

    *(bf16x8*)&A[row * A_STRIDE + seg * 16]     = pack8(P.v0, P.v1);
    *(bf16x8*)&A[row * A_STRIDE + seg * 16 + 8] = pack8(P.v2, P.v3);
    float4* ngp = (float4*)&NG[row * NG_STRIDE + seg * 16];
    ngp[0] = scale4(P.u0, g_row); ngp[1] = scale4(P.u1, g_row);
    ngp[2] = scale4(P.u2, g_row); ngp[3] = scale4(P.u3, g_row);

    float tc0 = P.t0, tc1 = P.t1;

    __syncthreads();

    // ---- refill P for n_next (lands 2 iterations from now) ----
    load_node(P, n_next, row, seg, w, el, link_vecs, neigh_vecs, select_probs, ts, tsf);

    // ---- MFMA: C[m][e] = link_row_m . W[:,e] ----
    f32x4 acc[2][2] = {};
#pragma unroll
    for (int s = 0; s < 4; ++s) {
        bf16x8 a0 = *(const bf16x8*)&A[(el)      * A_STRIDE + 32 * s + 8 * q];
        bf16x8 a1 = *(const bf16x8*)&A[(16 + el) * A_STRIDE + 32 * s + 8 * q];
        acc[0][0] = __builtin_amdgcn_mfma_f32_16x16x32_bf16(a0, wf[0][s], acc[0][0], 0, 0, 0);
        acc[0][1] = __builtin_amdgcn_mfma_f32_16x16x32_bf16(a0, wf[1][s], acc[0][1], 0, 0, 0);
        acc[1][0] = __builtin_amdgcn_mfma_f32_16x16x32_bf16(a1, wf[0][s], acc[1][0], 0, 0, 0);
        acc[1][1] = __builtin_amdgcn_mfma_f32_16x16x32_bf16(a1, wf[1][s], acc[1][1], 0, 0, 0);
    }

    // ---- epilogue: sigmoid(C) * (neigh*g), reduce over 32 rows ----
#pragma unroll
    for (int nt = 0; nt < 2; ++nt) {
        int c0 = 32 * w + 16 * nt;
        float s = 0.0f;
#pragma unroll
        for (int mt = 0; mt < 2; ++mt)
#pragma unroll
            for (int r = 0; r < 4; ++r) {
                int m = 16 * mt + 4 * q + r;
                s += sigm(acc[mt][nt][r]) * NG[m * NG_STRIDE + c0 + el];
            }
        s += __shfl_xor(s, 16);
        s += __shfl_xor(s, 32);
        if (q == 0) {
            float tc = nt == 0 ? tc0 : tc1;
            float o = tc * s;
            out[(size_t)n_cur * 128 + c0 + el] = o > 0.0f ? o : 0.0f;
        }
    }

    __syncthreads();  // guard LDS against next iteration's phase W
}

__global__ __launch_bounds__(256, 2) void aggregate_kernel(
    const float* __restrict__ neigh_vecs,
    const float* __restrict__ link_vecs,
    const float* __restrict__ select_probs,
    const float* __restrict__ gate_neigh_w,
    const float* __restrict__ gate_link_w,
    const float* __restrict__ link_weights,
    const float* __restrict__ tsf,
    const float* __restrict__ ts,
    float* __restrict__ out)
{
    __shared__ __align__(16) unsigned short A[32 * A_STRIDE];
    __shared__ __align__(16) float NG[32 * NG_STRIDE];

    const int tid  = threadIdx.x;
    const int lane = tid & 63;
    const int w    = tid >> 6;
    const int q    = lane >> 4;
    const int el   = lane & 15;
    const int row  = tid >> 3;
    const int seg  = tid & 7;

    // link_weights B-fragments: registers for the whole block
    bf16x8 wf[2][4];
#pragma unroll
    for (int nt = 0; nt < 2; ++nt) {
        int e = 32 * w + 16 * nt + el;
#pragma unroll
        for (int s = 0; s < 4; ++s) {
#pragma unroll
            for (int j = 0; j < 8; ++j) {
                int d = 32 * s + 8 * q + j;
                wf[nt][s][j] = (short)f2bf(link_weights[d * 128 + e]);
            }
        }
    }

    const float4* glp = (const float4*)(gate_link_w + seg * 16);
    float4 gl0 = glp[0], gl1 = glp[1], gl2 = glp[2], gl3 = glp[3];
    const float4* gnp = (const float4*)(gate_neigh_w + seg * 16);
    float4 gn0 = gnp[0], gn1 = gnp[1], gn2 = gnp[2], gn3 = gnp[3];

    const int stride = gridDim.x;

    // ---- prologue: fill both prefetch sets ----
    Pref PA, PB;
    int n = blockIdx.x;
    load_node(PA, n, row, seg, w, el, link_vecs, neigh_vecs, select_probs, ts, tsf);
    {
        int n1 = n + stride;
        load_node(PB, (n1 < N_NODES) ? n1 : n, row, seg, w, el,
                  link_vecs, neigh_vecs, select_probs, ts, tsf);
    }

    for (;;) {
        int n2 = n + 2 * stride;
        process_node(PA, n, (n2 < N_NODES) ? n2 : n, row, seg, w, q, el,
                     A, NG, wf, gl0, gl1, gl2, gl3, gn0, gn1, gn2, gn3,
                     link_vecs, neigh_vecs, select_probs, ts, tsf, out);
        n += stride;
        if (n >= N_NODES) break;

        n2 = n + 2 * stride;
        process_node(PB, n, (n2 < N_NODES) ? n2 : n, row, seg, w, q, el,
                     A, NG, wf, gl0, gl1, gl2, gl3, gn0, gn1, gn2, gn3,
                     link_vecs, neigh_vecs, select_probs, ts, tsf, out);
        n += stride;
        if (n >= N_NODES) break;
    }
}

extern "C" void kernel_launch(void* const* d_in, const int* in_sizes, int n_in,
                              void* d_out, int out_size, void* d_ws, size_t ws_size,
                              hipStream_t stream) {
    const float* self_feats   = (const float*)d_in[0];
    const float* self_vecs    = (const float*)d_in[1];
    const float* neigh_vecs   = (const float*)d_in[2];
    const float* link_vecs    = (const float*)d_in[3];
    const float* select_probs = (const float*)d_in[4];
    const float* gate_self_w  = (const float*)d_in[5];
    const float* gate_neigh_w = (const float*)d_in[6];
    const float* gate_link_w  = (const float*)d_in[7];
    const float* self_weights = (const float*)d_in[8];
    const float* link_weights = (const float*)d_in[9];
    float* out = (float*)d_out;

    float* tsf = (float*)d_ws;                       // [N,128] fp32
    float* ts  = tsf + (size_t)N_NODES * D_DIM;      // [N] fp32

    precompute_kernel<<<N_NODES / 32, 256, 0, stream>>>(
        self_feats, self_vecs, gate_self_w, self_weights, tsf, ts);
    aggregate_kernel<<<2048, 256, 0, stream>>>(
        neigh_vecs, link_vecs, select_probs, gate_neigh_w, gate_link_w,
        link_weights, tsf, ts, out);
}

// Round 3
// 657.357 us; speedup vs baseline: 1.0069x; 1.0055x over previous
//
#include <hip/hip_runtime.h>
#include <stdint.h>

#define N_NODES 20000
#define K_NB 32
#define D_DIM 128

typedef short bf16x8 __attribute__((ext_vector_type(8)));
typedef float f32x4 __attribute__((ext_vector_type(4)));

// fp32 -> bf16 round-to-nearest-even
__device__ __forceinline__ unsigned short f2bf(float f) {
    union { float f; unsigned u; } v; v.f = f;
    unsigned r = v.u + 0x7FFFu + ((v.u >> 16) & 1u);
    return (unsigned short)(r >> 16);
}

__device__ __forceinline__ bf16x8 pack8(float4 a, float4 b) {
    bf16x8 r;
    r[0] = (short)f2bf(a.x); r[1] = (short)f2bf(a.y);
    r[2] = (short)f2bf(a.z); r[3] = (short)f2bf(a.w);
    r[4] = (short)f2bf(b.x); r[5] = (short)f2bf(b.y);
    r[6] = (short)f2bf(b.z); r[7] = (short)f2bf(b.w);
    return r;
}

__device__ __forceinline__ float dot16(float4 a0, float4 a1, float4 a2, float4 a3,
                                       float4 b0, float4 b1, float4 b2, float4 b3) {
    return a0.x*b0.x + a0.y*b0.y + a0.z*b0.z + a0.w*b0.w
         + a1.x*b1.x + a1.y*b1.y + a1.z*b1.z + a1.w*b1.w
         + a2.x*b2.x + a2.y*b2.y + a2.z*b2.z + a2.w*b2.w
         + a3.x*b3.x + a3.y*b3.y + a3.z*b3.z + a3.w*b3.w;
}

__device__ __forceinline__ float sigm(float x) {
    return __builtin_amdgcn_rcpf(1.0f + __expf(-x));
}

__device__ __forceinline__ float4 scale4(float4 a, float s) {
    float4 r; r.x = a.x*s; r.y = a.y*s; r.z = a.z*s; r.w = a.w*s; return r;
}

// Raw barrier that does NOT drain vmcnt: LDS ops must be complete/visible
// (lgkmcnt(0)) but register-destined global prefetch loads stay in flight.
// __syncthreads() would emit s_waitcnt vmcnt(0) and kill the pipeline.
__device__ __forceinline__ void barrier_lds_only() {
    asm volatile("s_waitcnt lgkmcnt(0)" ::: "memory");
    __builtin_amdgcn_s_barrier();
    asm volatile("" ::: "memory");
}

#define A_STRIDE 136
#define NG_STRIDE 132

// ---------------------------------------------------------------------------
// Kernel 1: tsf[n,e] = self_feats @ self_weights ; ts[n] = self_vecs . gate_self_w
// ---------------------------------------------------------------------------
__global__ __launch_bounds__(256) void precompute_kernel(
    const float* __restrict__ self_feats,
    const float* __restrict__ self_vecs,
    const float* __restrict__ gate_self_w,
    const float* __restrict__ self_weights,
    float* __restrict__ tsf,
    float* __restrict__ ts)
{
    __shared__ __align__(16) unsigned short A[32 * A_STRIDE];

    const int tid  = threadIdx.x;
    const int lane = tid & 63;
    const int w    = tid >> 6;
    const int q    = lane >> 4;
    const int el   = lane & 15;
    const int row  = tid >> 3;
    const int seg  = tid & 7;
    const int node0 = blockIdx.x * 32;

    bf16x8 wf[2][4];
#pragma unroll
    for (int nt = 0; nt < 2; ++nt) {
        int e = 32 * w + 16 * nt + el;
#pragma unroll
        for (int s = 0; s < 4; ++s) {
#pragma unroll
            for (int j = 0; j < 8; ++j) {
                int d = 32 * s + 8 * q + j;
                wf[nt][s][j] = (short)f2bf(self_weights[d * 128 + e]);
            }
        }
    }

    const float4* gs = (const float4*)(gate_self_w + seg * 16);
    float4 g0 = gs[0], g1 = gs[1], g2 = gs[2], g3 = gs[3];

    {
        const float4* sfr = (const float4*)(self_feats + (size_t)(node0 + row) * 128 + seg * 16);
        float4 v0 = sfr[0], v1 = sfr[1], v2 = sfr[2], v3 = sfr[3];
        const float4* svr = (const float4*)(self_vecs + (size_t)(node0 + row) * 128 + seg * 16);
        float4 u0 = svr[0], u1 = svr[1], u2 = svr[2], u3 = svr[3];

        float part = dot16(u0, u1, u2, u3, g0, g1, g2, g3);
        part += __shfl_xor(part, 1);
        part += __shfl_xor(part, 2);
        part += __shfl_xor(part, 4);
        if (seg == 0) ts[node0 + row] = part;

        *(bf16x8*)&A[row * A_STRIDE + seg * 16]     = pack8(v0, v1);
        *(bf16x8*)&A[row * A_STRIDE + seg * 16 + 8] = pack8(v2, v3);
    }
    __syncthreads();

    f32x4 acc[2][2] = {};
#pragma unroll
    for (int s = 0; s < 4; ++s) {
        bf16x8 a0 = *(const bf16x8*)&A[(el)      * A_STRIDE + 32 * s + 8 * q];
        bf16x8 a1 = *(const bf16x8*)&A[(16 + el) * A_STRIDE + 32 * s + 8 * q];
        acc[0][0] = __builtin_amdgcn_mfma_f32_16x16x32_bf16(a0, wf[0][s], acc[0][0], 0, 0, 0);
        acc[0][1] = __builtin_amdgcn_mfma_f32_16x16x32_bf16(a0, wf[1][s], acc[0][1], 0, 0, 0);
        acc[1][0] = __builtin_amdgcn_mfma_f32_16x16x32_bf16(a1, wf[0][s], acc[1][0], 0, 0, 0);
        acc[1][1] = __builtin_amdgcn_mfma_f32_16x16x32_bf16(a1, wf[1][s], acc[1][1], 0, 0, 0);
    }

#pragma unroll
    for (int mt = 0; mt < 2; ++mt)
#pragma unroll
        for (int nt = 0; nt < 2; ++nt)
#pragma unroll
            for (int r = 0; r < 4; ++r) {
                int m = 16 * mt + 4 * q + r;
                tsf[(size_t)(node0 + m) * 128 + 32 * w + 16 * nt + el] = acc[mt][nt][r];
            }
}

// ---------------------------------------------------------------------------
// Kernel 2: fused aggregation, 2-deep register prefetch + NON-DRAINING
// barriers. The node loop's two block barriers wait lgkmcnt(0) only
// (raw s_barrier); prefetch global loads issued in phase W stay in flight
// across BOTH barriers and land at next iteration's compiler-inserted
// vmcnt waits. (__syncthreads drained vmcnt(0) every iteration -> memory
// queue duty cycle ~45% -> invariant 1.84 TB/s in rounds 1-2.)
// ---------------------------------------------------------------------------
struct Pref {
    float4 v0, v1, v2, v3;   // link_vecs row slice
    float4 u0, u1, u2, u3;   // neigh_vecs row slice
    float sp, ts, t0, t1;
};

__device__ __forceinline__ void load_node(
    Pref& P, int n, int row, int seg, int w, int el,
    const float* __restrict__ link_vecs, const float* __restrict__ neigh_vecs,
    const float* __restrict__ select_probs, const float* __restrict__ ts,
    const float* __restrict__ tsf)
{
    const float4* lr = (const float4*)(link_vecs + ((size_t)n * 32 + row) * 128 + seg * 16);
    P.v0 = lr[0]; P.v1 = lr[1]; P.v2 = lr[2]; P.v3 = lr[3];
    const float4* nr = (const float4*)(neigh_vecs + ((size_t)n * 32 + row) * 128 + seg * 16);
    P.u0 = nr[0]; P.u1 = nr[1]; P.u2 = nr[2]; P.u3 = nr[3];
    P.sp = select_probs[(size_t)n * 32 + row];   // 8 threads/row broadcast-read
    P.ts = ts[n];
    P.t0 = tsf[(size_t)n * 128 + 32 * w + el];
    P.t1 = tsf[(size_t)n * 128 + 32 * w + 16 + el];
}

__device__ __forceinline__ void process_node(
    Pref& P, int n_cur, int n_next,
    int row, int seg, int w, int q, int el,
    unsigned short* A, float* NG,
    const bf16x8 (&wf)[2][4],
    float4 gl0, float4 gl1, float4 gl2, float4 gl3,
    float4 gn0, float4 gn1, float4 gn2, float4 gn3,
    const float* __restrict__ link_vecs, const float* __restrict__ neigh_vecs,
    const float* __restrict__ select_probs, const float* __restrict__ ts,
    const float* __restrict__ tsf, float* __restrict__ out)
{
    // ---- phase W: gate dots + stage prefetched regs into LDS ----
    float tl = dot16(P.v0, P.v1, P.v2, P.v3, gl0, gl1, gl2, gl3);
    tl += __shfl_xor(tl, 1);
    tl += __shfl_xor(tl, 2);
    tl += __shfl_xor(tl, 4);
    float tn = dot16(P.u0, P.u1, P.u2, P.u3, gn0, gn1, gn2, gn3);
    tn += __shfl_xor(tn, 1);
    tn += __shfl_xor(tn, 2);
    tn += __shfl_xor(tn, 4);
    // all 8 seg-threads of this row hold the full gate sum -> premultiply
    float g_row = sigm(P.ts + tl + tn) * __builtin_amdgcn_rcpf(32.0f * P.sp);

    *(bf16x8*)&A[row * A_STRIDE + seg * 16]     = pack8(P.v0, P.v1);
    *(bf16x8*)&A[row * A_STRIDE + seg * 16 + 8] = pack8(P.v2, P.v3);
    float4* ngp = (float4*)&NG[row * NG_STRIDE + seg * 16];
    ngp[0] = scale4(P.u0, g_row); ngp[1] = scale4(P.u1, g_row);
    ngp[2] = scale4(P.u2, g_row); ngp[3] = scale4(P.u3, g_row);

    float tc0 = P.t0, tc1 = P.t1;

    // ---- issue next node's burst BEFORE the barrier (waves parked at the
    // barrier already have their 32KB in flight) ----
    load_node(P, n_next, row, seg, w, el, link_vecs, neigh_vecs, select_probs, ts, tsf);

    barrier_lds_only();   // LDS visible; vmem NOT drained

    // ---- MFMA: C[m][e] = link_row_m . W[:,e] ----
    f32x4 acc[2][2] = {};
#pragma unroll
    for (int s = 0; s < 4; ++s) {
        bf16x8 a0 = *(const bf16x8*)&A[(el)      * A_STRIDE + 32 * s + 8 * q];
        bf16x8 a1 = *(const bf16x8*)&A[(16 + el) * A_STRIDE + 32 * s + 8 * q];
        acc[0][0] = __builtin_amdgcn_mfma_f32_16x16x32_bf16(a0, wf[0][s], acc[0][0], 0, 0, 0);
        acc[0][1] = __builtin_amdgcn_mfma_f32_16x16x32_bf16(a0, wf[1][s], acc[0][1], 0, 0, 0);
        acc[1][0] = __builtin_amdgcn_mfma_f32_16x16x32_bf16(a1, wf[0][s], acc[1][0], 0, 0, 0);
        acc[1][1] = __builtin_amdgcn_mfma_f32_16x16x32_bf16(a1, wf[1][s], acc[1][1], 0, 0, 0);
    }

    // ---- epilogue: sigmoid(C) * (neigh*g), reduce over 32 rows ----
#pragma unroll
    for (int nt = 0; nt < 2; ++nt) {
        int c0 = 32 * w + 16 * nt;
        float s = 0.0f;
#pragma unroll
        for (int mt = 0; mt < 2; ++mt)
#pragma unroll
            for (int r = 0; r < 4; ++r) {
                int m = 16 * mt + 4 * q + r;
                s += sigm(acc[mt][nt][r]) * NG[m * NG_STRIDE + c0 + el];
            }
        s += __shfl_xor(s, 16);
        s += __shfl_xor(s, 32);
        if (q == 0) {
            float tc = nt == 0 ? tc0 : tc1;
            float o = tc * s;
            out[(size_t)n_cur * 128 + c0 + el] = o > 0.0f ? o : 0.0f;
        }
    }

    barrier_lds_only();   // guard LDS against next iteration's phase W
}

__global__ __launch_bounds__(256, 2) void aggregate_kernel(
    const float* __restrict__ neigh_vecs,
    const float* __restrict__ link_vecs,
    const float* __restrict__ select_probs,
    const float* __restrict__ gate_neigh_w,
    const float* __restrict__ gate_link_w,
    const float* __restrict__ link_weights,
    const float* __restrict__ tsf,
    const float* __restrict__ ts,
    float* __restrict__ out)
{
    __shared__ __align__(16) unsigned short A[32 * A_STRIDE];
    __shared__ __align__(16) float NG[32 * NG_STRIDE];

    const int tid  = threadIdx.x;
    const int lane = tid & 63;
    const int w    = tid >> 6;
    const int q    = lane >> 4;
    const int el   = lane & 15;
    const int row  = tid >> 3;
    const int seg  = tid & 7;

    // link_weights B-fragments: registers for the whole block
    bf16x8 wf[2][4];
#pragma unroll
    for (int nt = 0; nt < 2; ++nt) {
        int e = 32 * w + 16 * nt + el;
#pragma unroll
        for (int s = 0; s < 4; ++s) {
#pragma unroll
            for (int j = 0; j < 8; ++j) {
                int d = 32 * s + 8 * q + j;
                wf[nt][s][j] = (short)f2bf(link_weights[d * 128 + e]);
            }
        }
    }

    const float4* glp = (const float4*)(gate_link_w + seg * 16);
    float4 gl0 = glp[0], gl1 = glp[1], gl2 = glp[2], gl3 = glp[3];
    const float4* gnp = (const float4*)(gate_neigh_w + seg * 16);
    float4 gn0 = gnp[0], gn1 = gnp[1], gn2 = gnp[2], gn3 = gnp[3];

    const int stride = gridDim.x;

    // ---- prologue: fill both prefetch sets ----
    Pref PA, PB;
    int n = blockIdx.x;
    load_node(PA, n, row, seg, w, el, link_vecs, neigh_vecs, select_probs, ts, tsf);
    {
        int n1 = n + stride;
        load_node(PB, (n1 < N_NODES) ? n1 : n, row, seg, w, el,
                  link_vecs, neigh_vecs, select_probs, ts, tsf);
    }

    for (;;) {
        int n2 = n + 2 * stride;
        process_node(PA, n, (n2 < N_NODES) ? n2 : n, row, seg, w, q, el,
                     A, NG, wf, gl0, gl1, gl2, gl3, gn0, gn1, gn2, gn3,
                     link_vecs, neigh_vecs, select_probs, ts, tsf, out);
        n += stride;
        if (n >= N_NODES) break;

        n2 = n + 2 * stride;
        process_node(PB, n, (n2 < N_NODES) ? n2 : n, row, seg, w, q, el,
                     A, NG, wf, gl0, gl1, gl2, gl3, gn0, gn1, gn2, gn3,
                     link_vecs, neigh_vecs, select_probs, ts, tsf, out);
        n += stride;
        if (n >= N_NODES) break;
    }
}

extern "C" void kernel_launch(void* const* d_in, const int* in_sizes, int n_in,
                              void* d_out, int out_size, void* d_ws, size_t ws_size,
                              hipStream_t stream) {
    const float* self_feats   = (const float*)d_in[0];
    const float* self_vecs    = (const float*)d_in[1];
    const float* neigh_vecs   = (const float*)d_in[2];
    const float* link_vecs    = (const float*)d_in[3];
    const float* select_probs = (const float*)d_in[4];
    const float* gate_self_w  = (const float*)d_in[5];
    const float* gate_neigh_w = (const float*)d_in[6];
    const float* gate_link_w  = (const float*)d_in[7];
    const float* self_weights = (const float*)d_in[8];
    const float* link_weights = (const float*)d_in[9];
    float* out = (float*)d_out;

    float* tsf = (float*)d_ws;                       // [N,128] fp32
    float* ts  = tsf + (size_t)N_NODES * D_DIM;      // [N] fp32

    precompute_kernel<<<N_NODES / 32, 256, 0, stream>>>(
        self_feats, self_vecs, gate_self_w, self_weights, tsf, ts);
    aggregate_kernel<<<2048, 256, 0, stream>>>(
        neigh_vecs, link_vecs, select_probs, gate_neigh_w, gate_link_w,
        link_weights, tsf, ts, out);
}